// Round 9
// baseline (960.944 us; speedup 1.0000x reference)
//
#include <hip/hip_runtime.h>

// ---------------------------------------------------------------------------
// Hetero 2-layer GraphSAGE — CSR-gather, round 9.
//
// Round-8 lesson (rocprof): pretransform_v3 is LDS-issue-bound (VALUBusy 21%,
// occ 26%, 1.4 TB/s; 832 LDS insts/wave: 12 uniform b128 weight reads per k
// feeding only 48 FMA/thread; ~30 waves/CU x 830 x ~8cyc ~= the 113 us).
// Fix: pretransform_v4 — 2 nodes/thread (512/block), 16-col quarter staging
// (xs[512][17], same 3 blocks/CU): the same 12 weight reads per k now feed
// 192 FMAs; LDS insts/node 13 -> 7.25. Accumulation order bit-identical.
// Everything else FROZEN (hists intentionally stay split so the next top-5
// finally ranks the gather dispatches).
// ---------------------------------------------------------------------------

#define N_DEV   100000
#define N_TASK  500000
#define NEDGE   1000000
#define NCNT    1200000          // 500K (wr) + 500K (rv) + 100K (wb) + 100K (rb)
#define BASE_WR 0
#define BASE_RV 500000
#define BASE_WB 1000000
#define BASE_RB 1100000

#define SCAN_PER   16
#define SCAN_CHUNK 4096          // 256 threads * 16
#define SCAN_NBLK  293           // ceil(1.2M / 4096)

// ---- CSR step 1: per-relation histogram + per-edge rank capture ----
__global__ __launch_bounds__(256) void hist_rank_rel(
    const int* __restrict__ dst, int base,
    int* __restrict__ cnt, int* __restrict__ rank)
{
    const int e = blockIdx.x * 256 + threadIdx.x;
    if (e >= NEDGE) return;
    const int d = __builtin_nontemporal_load(dst + e);
    rank[e] = atomicAdd(&cnt[base + d], 1);
}

// ---- CSR step 2a: per-block sums of counters ----
__global__ __launch_bounds__(256) void scan_block_sums(
    const int* __restrict__ c, int* __restrict__ bsum)
{
    __shared__ int sm[256];
    const int t = threadIdx.x;
    const int base = blockIdx.x * SCAN_CHUNK + t * SCAN_PER;
    int s = 0;
#pragma unroll
    for (int k = 0; k < SCAN_PER; k += 4) {
        const int idx = base + k;
        if (idx + 3 < NCNT) {
            const int4 v = *reinterpret_cast<const int4*>(&c[idx]);
            s += v.x + v.y + v.z + v.w;
        } else {
            for (int q = 0; q < 4; ++q) if (idx + q < NCNT) s += c[idx + q];
        }
    }
    sm[t] = s;
    __syncthreads();
    for (int off = 128; off > 0; off >>= 1) {
        if (t < off) sm[t] += sm[t + off];
        __syncthreads();
    }
    if (t == 0) bsum[blockIdx.x] = sm[0];
}

// ---- CSR step 2b: exclusive scan of block sums (single block) ----
__global__ __launch_bounds__(512) void scan_bsum(int* __restrict__ bsum)
{
    __shared__ int sm[512];
    const int t = threadIdx.x;
    const int own = (t < SCAN_NBLK) ? bsum[t] : 0;
    sm[t] = own;
    __syncthreads();
    for (int off = 1; off < 512; off <<= 1) {
        int v = sm[t];
        if (t >= off) v += sm[t - off];
        __syncthreads();
        sm[t] = v;
        __syncthreads();
    }
    if (t < SCAN_NBLK) bsum[t] = sm[t] - own;   // exclusive
}

// ---- CSR step 2c: final exclusive scan -> row_ptr ----
__global__ __launch_bounds__(256) void scan_final(
    const int* __restrict__ c, const int* __restrict__ bsum,
    int* __restrict__ rp)
{
    __shared__ int sm[256];
    const int t = threadIdx.x;
    const int base = blockIdx.x * SCAN_CHUNK + t * SCAN_PER;
    int vals[SCAN_PER];
    int s = 0;
#pragma unroll
    for (int k = 0; k < SCAN_PER; k += 4) {
        const int idx = base + k;
        int4 v = make_int4(0, 0, 0, 0);
        if (idx + 3 < NCNT) {
            v = *reinterpret_cast<const int4*>(&c[idx]);
        } else {
            if (idx + 0 < NCNT) v.x = c[idx + 0];
            if (idx + 1 < NCNT) v.y = c[idx + 1];
            if (idx + 2 < NCNT) v.z = c[idx + 2];
            if (idx + 3 < NCNT) v.w = c[idx + 3];
        }
        vals[k + 0] = v.x; vals[k + 1] = v.y; vals[k + 2] = v.z; vals[k + 3] = v.w;
        s += v.x + v.y + v.z + v.w;
    }
    const int own = s;
    sm[t] = own;
    __syncthreads();
    for (int off = 1; off < 256; off <<= 1) {
        int v = sm[t];
        if (t >= off) v += sm[t - off];
        __syncthreads();
        sm[t] = v;
        __syncthreads();
    }
    int run = sm[t] - own + bsum[blockIdx.x];
#pragma unroll
    for (int k = 0; k < SCAN_PER; ++k) {
        if (base + k < NCNT) rp[base + k] = run;
        run += vals[k];
    }
    if (blockIdx.x == 0 && t == 0) rp[NCNT] = 4 * NEDGE;
}

// ---- CSR step 3: per-relation fill, atomic-free via rank ----
__global__ __launch_bounds__(256) void fill_rel(
    const int* __restrict__ src, const int* __restrict__ dst,
    const int* __restrict__ rank, int base,
    const int* __restrict__ rp, int* __restrict__ eidx)
{
    const int e = blockIdx.x * 256 + threadIdx.x;
    if (e >= NEDGE) return;
    const int d = __builtin_nontemporal_load(dst + e);
    const int s = __builtin_nontemporal_load(src + e);
    const int r = __builtin_nontemporal_load(rank + e);
    eidx[rp[base + d] + r] = s;
}

// ---- pretransform v4: 2 nodes/thread, 16-col quarter LDS staging.
// outA = x@WA, outB = x@WB, outC = x@(WC1+WC2). 512 nodes/block.
__global__ __launch_bounds__(256) void pretransform_v4(
    const float* __restrict__ x,
    const float* __restrict__ WA, const float* __restrict__ WB,
    const float* __restrict__ WC1, const float* __restrict__ WC2,
    float* __restrict__ outA, float* __restrict__ outB, float* __restrict__ outC,
    int n)
{
    __shared__ float xs[512][17];                 // 16 cols + 1 pad (34.8 KB)
    __shared__ float wAs[1024], wBs[1024], wCs[1024];

    const int t = threadIdx.x;
    for (int i = t; i < 1024; i += 256) {
        wAs[i] = WA[i];
        wBs[i] = WB[i];
        wCs[i] = WC1[i] + WC2[i];
    }

    const int node0 = blockIdx.x * 512;
    const int nrow  = min(512, n - node0);

    float a0[16], b0[16], c0[16], a1[16], b1[16], c1[16];
#pragma unroll
    for (int i = 0; i < 16; ++i) {
        a0[i] = b0[i] = c0[i] = 0.f;
        a1[i] = b1[i] = c1[i] = 0.f;
    }

    for (int q = 0; q < 4; ++q) {
        __syncthreads();   // xs reuse barrier (covers w staging on q=0)
        // stage cols [q*16, q*16+16) for nrow rows: 2048 float4, 8/thread
#pragma unroll
        for (int it = 0; it < 8; ++it) {
            const int idx = it * 256 + t;         // float4 index 0..2047
            const int r = idx >> 2, c4 = idx & 3;
            if (r < nrow) {
                const float4 v = *reinterpret_cast<const float4*>(
                    &x[(size_t)(node0 + r) * 64 + q * 16 + c4 * 4]);
                xs[r][c4 * 4 + 0] = v.x;
                xs[r][c4 * 4 + 1] = v.y;
                xs[r][c4 * 4 + 2] = v.z;
                xs[r][c4 * 4 + 3] = v.w;
            }
        }
        __syncthreads();

        for (int kk = 0; kk < 16; ++kk) {
            const int k = q * 16 + kk;
            const float xv0 = xs[t][kk];
            const float xv1 = xs[t + 256][kk];
            const float4* wa4 = reinterpret_cast<const float4*>(&wAs[k * 16]);
            const float4* wb4 = reinterpret_cast<const float4*>(&wBs[k * 16]);
            const float4* wc4 = reinterpret_cast<const float4*>(&wCs[k * 16]);
#pragma unroll
            for (int qd = 0; qd < 4; ++qd) {
                const float4 wa = wa4[qd], wb = wb4[qd], wc = wc4[qd];
                a0[qd*4+0] = fmaf(xv0, wa.x, a0[qd*4+0]);
                a0[qd*4+1] = fmaf(xv0, wa.y, a0[qd*4+1]);
                a0[qd*4+2] = fmaf(xv0, wa.z, a0[qd*4+2]);
                a0[qd*4+3] = fmaf(xv0, wa.w, a0[qd*4+3]);
                b0[qd*4+0] = fmaf(xv0, wb.x, b0[qd*4+0]);
                b0[qd*4+1] = fmaf(xv0, wb.y, b0[qd*4+1]);
                b0[qd*4+2] = fmaf(xv0, wb.z, b0[qd*4+2]);
                b0[qd*4+3] = fmaf(xv0, wb.w, b0[qd*4+3]);
                c0[qd*4+0] = fmaf(xv0, wc.x, c0[qd*4+0]);
                c0[qd*4+1] = fmaf(xv0, wc.y, c0[qd*4+1]);
                c0[qd*4+2] = fmaf(xv0, wc.z, c0[qd*4+2]);
                c0[qd*4+3] = fmaf(xv0, wc.w, c0[qd*4+3]);
                a1[qd*4+0] = fmaf(xv1, wa.x, a1[qd*4+0]);
                a1[qd*4+1] = fmaf(xv1, wa.y, a1[qd*4+1]);
                a1[qd*4+2] = fmaf(xv1, wa.z, a1[qd*4+2]);
                a1[qd*4+3] = fmaf(xv1, wa.w, a1[qd*4+3]);
                b1[qd*4+0] = fmaf(xv1, wb.x, b1[qd*4+0]);
                b1[qd*4+1] = fmaf(xv1, wb.y, b1[qd*4+1]);
                b1[qd*4+2] = fmaf(xv1, wb.z, b1[qd*4+2]);
                b1[qd*4+3] = fmaf(xv1, wb.w, b1[qd*4+3]);
                c1[qd*4+0] = fmaf(xv1, wc.x, c1[qd*4+0]);
                c1[qd*4+1] = fmaf(xv1, wc.y, c1[qd*4+1]);
                c1[qd*4+2] = fmaf(xv1, wc.z, c1[qd*4+2]);
                c1[qd*4+3] = fmaf(xv1, wc.w, c1[qd*4+3]);
            }
        }
    }

    {   // node t
        const int node = node0 + t;
        if (t < nrow) {
            float4* oA = reinterpret_cast<float4*>(&outA[(size_t)node * 16]);
            float4* oB = reinterpret_cast<float4*>(&outB[(size_t)node * 16]);
            float4* oC = reinterpret_cast<float4*>(&outC[(size_t)node * 16]);
#pragma unroll
            for (int i = 0; i < 4; ++i) {
                oA[i] = make_float4(a0[i*4], a0[i*4+1], a0[i*4+2], a0[i*4+3]);
                oB[i] = make_float4(b0[i*4], b0[i*4+1], b0[i*4+2], b0[i*4+3]);
                oC[i] = make_float4(c0[i*4], c0[i*4+1], c0[i*4+2], c0[i*4+3]);
            }
        }
    }
    {   // node t + 256
        const int node = node0 + 256 + t;
        if (256 + t < nrow) {
            float4* oA = reinterpret_cast<float4*>(&outA[(size_t)node * 16]);
            float4* oB = reinterpret_cast<float4*>(&outB[(size_t)node * 16]);
            float4* oC = reinterpret_cast<float4*>(&outC[(size_t)node * 16]);
#pragma unroll
            for (int i = 0; i < 4; ++i) {
                oA[i] = make_float4(a1[i*4], a1[i*4+1], a1[i*4+2], a1[i*4+3]);
                oB[i] = make_float4(b1[i*4], b1[i*4+1], b1[i*4+2], b1[i*4+3]);
                oC[i] = make_float4(c1[i*4], c1[i*4+1], c1[i*4+2], c1[i*4+3]);
            }
        }
    }
}

// ---- lean mean gather: one feature dim j per call site, uint addressing ----
__device__ __forceinline__ float gather_mean_j(
    const float* __restrict__ h, const int* __restrict__ eidx,
    int e0, int e1, int j)
{
    float acc = 0.f;
    int e = e0;
    for (; e + 2 <= e1; e += 2) {
        const unsigned s0 = (unsigned)eidx[e] << 4;
        const unsigned s1 = (unsigned)eidx[e + 1] << 4;
        acc += h[s0 + j] + h[s1 + j];
    }
    if (e < e1) acc += h[((unsigned)eidx[e] << 4) + j];
    return acc * (1.f / fmaxf((float)(e1 - e0), 1.f));
}

// ---- L1 gather v3: 32 lanes/node (16 per relation), diet addressing ----
__global__ __launch_bounds__(256) void gather_l1_v3(
    const float* __restrict__ hA, const float* __restrict__ hB,
    const int* __restrict__ rp, const int* __restrict__ eidx,
    int baseA, int baseB,
    const float* __restrict__ root,
    const float* __restrict__ bA, const float* __restrict__ bB,
    float* __restrict__ out, int n)
{
    const int t = threadIdx.x;
    const int sub = t & 31;          // lane within 32-group
    const int rel = sub >> 4;        // 0 = A, 1 = B
    const int j   = sub & 15;
    const int i   = blockIdx.x * 8 + (t >> 5);
    if (i >= n) return;

    const int b = rel ? baseB : baseA;
    const int e0 = rp[b + i];
    const int e1 = rp[b + i + 1];
    const float* h = rel ? hB : hA;

    float m = gather_mean_j(h, eidx, e0, e1, j);
    m += __shfl_xor(m, 16, 32);      // mA + mB in both halves

    if (rel == 0) {
        const unsigned o = ((unsigned)i << 4) + j;
        out[o] = fmaxf(m + root[o] + bA[j] + bB[j], 0.f);
    }
}

// ---- L2 gather v3 + 16->32 matmul. 32 nodes/block, 8 lanes/node gather,
//      4 cols/thread matmul (float4 W reads, float4 store). ----
__global__ __launch_bounds__(256) void gather_l2_v3(
    const float* __restrict__ hA, const float* __restrict__ hB,
    const int* __restrict__ rp, const int* __restrict__ eidx,
    int baseA, int baseB,
    const float* __restrict__ xroot,
    const float* __restrict__ WA, const float* __restrict__ WB,
    const float* __restrict__ WR1, const float* __restrict__ WR2,
    const float* __restrict__ bA, const float* __restrict__ bB,
    float* __restrict__ out, int n)
{
    __shared__ float wA[512], wB[512], wR[512], bs[32];
    __shared__ float smA[32][17], smB[32][17], smR[32][17];

    const int t = threadIdx.x;
    for (int q = t; q < 512; q += 256) {
        wA[q] = WA[q];
        wB[q] = WB[q];
        wR[q] = WR1[q] + WR2[q];
    }
    if (t < 32) bs[t] = bA[t] + bB[t];

    const int g = t >> 3;            // node slot 0..31
    const int j = t & 7;             // covers dims j and j+8
    const int i = blockIdx.x * 32 + g;

    if (i < n) {
        // relation A
        {
            const int e0 = rp[baseA + i], e1 = rp[baseA + i + 1];
            float m0 = 0.f, m1 = 0.f;
            int e = e0;
            for (; e + 2 <= e1; e += 2) {
                const unsigned s0 = (unsigned)eidx[e] << 4;
                const unsigned s1 = (unsigned)eidx[e + 1] << 4;
                m0 += hA[s0 + j]     + hA[s1 + j];
                m1 += hA[s0 + j + 8] + hA[s1 + j + 8];
            }
            if (e < e1) {
                const unsigned s = (unsigned)eidx[e] << 4;
                m0 += hA[s + j];
                m1 += hA[s + j + 8];
            }
            const float inv = 1.f / fmaxf((float)(e1 - e0), 1.f);
            smA[g][j]     = m0 * inv;
            smA[g][j + 8] = m1 * inv;
        }
        // relation B
        {
            const int e0 = rp[baseB + i], e1 = rp[baseB + i + 1];
            float m0 = 0.f, m1 = 0.f;
            int e = e0;
            for (; e + 2 <= e1; e += 2) {
                const unsigned s0 = (unsigned)eidx[e] << 4;
                const unsigned s1 = (unsigned)eidx[e + 1] << 4;
                m0 += hB[s0 + j]     + hB[s1 + j];
                m1 += hB[s0 + j + 8] + hB[s1 + j + 8];
            }
            if (e < e1) {
                const unsigned s = (unsigned)eidx[e] << 4;
                m0 += hB[s + j];
                m1 += hB[s + j + 8];
            }
            const float inv = 1.f / fmaxf((float)(e1 - e0), 1.f);
            smB[g][j]     = m0 * inv;
            smB[g][j + 8] = m1 * inv;
        }
        // root
        const unsigned ri = ((unsigned)i << 4) + j;
        smR[g][j]     = xroot[ri];
        smR[g][j + 8] = xroot[ri + 8];
    }
    __syncthreads();

    // matmul phase: node g2 = t>>3, cols [4p, 4p+3], one float4 per thread
    const int g2 = t >> 3;
    const int p  = t & 7;
    const int i2 = blockIdx.x * 32 + g2;
    if (i2 >= n) return;
    const int c0 = p * 4;
    float4 acc = *reinterpret_cast<const float4*>(&bs[c0]);
#pragma unroll
    for (int k = 0; k < 16; ++k) {
        const float a = smA[g2][k], b = smB[g2][k], r = smR[g2][k];
        const float4 wa = *reinterpret_cast<const float4*>(&wA[k * 32 + c0]);
        const float4 wb = *reinterpret_cast<const float4*>(&wB[k * 32 + c0]);
        const float4 wr = *reinterpret_cast<const float4*>(&wR[k * 32 + c0]);
        acc.x = fmaf(a, wa.x, acc.x);
        acc.x = fmaf(b, wb.x, acc.x);
        acc.x = fmaf(r, wr.x, acc.x);
        acc.y = fmaf(a, wa.y, acc.y);
        acc.y = fmaf(b, wb.y, acc.y);
        acc.y = fmaf(r, wr.y, acc.y);
        acc.z = fmaf(a, wa.z, acc.z);
        acc.z = fmaf(b, wb.z, acc.z);
        acc.z = fmaf(r, wr.z, acc.z);
        acc.w = fmaf(a, wa.w, acc.w);
        acc.w = fmaf(b, wb.w, acc.w);
        acc.w = fmaf(r, wr.w, acc.w);
    }
    *reinterpret_cast<float4*>(&out[(size_t)i2 * 32 + c0]) = acc;
}

extern "C" void kernel_launch(void* const* d_in, const int* in_sizes, int n_in,
                              void* d_out, int out_size, void* d_ws, size_t ws_size,
                              hipStream_t stream)
{
    const float* x_dev  = (const float*)d_in[0];
    const float* x_task = (const float*)d_in[1];
    const int* wr_src = (const int*)d_in[2];
    const int* wr_dst = (const int*)d_in[3];
    const int* rv_src = (const int*)d_in[4];
    const int* rv_dst = (const int*)d_in[5];
    const int* wb_src = (const int*)d_in[6];
    const int* wb_dst = (const int*)d_in[7];
    const int* rb_src = (const int*)d_in[8];
    const int* rb_dst = (const int*)d_in[9];
    const float* p1wr_wl = (const float*)d_in[10];
    const float* p1wr_bl = (const float*)d_in[11];
    const float* p1wr_wr = (const float*)d_in[12];
    const float* p1rv_wl = (const float*)d_in[13];
    const float* p1rv_bl = (const float*)d_in[14];
    const float* p1rv_wr = (const float*)d_in[15];
    const float* p1wb_wl = (const float*)d_in[16];
    const float* p1wb_bl = (const float*)d_in[17];
    const float* p1wb_wr = (const float*)d_in[18];
    const float* p1rb_wl = (const float*)d_in[19];
    const float* p1rb_bl = (const float*)d_in[20];
    const float* p1rb_wr = (const float*)d_in[21];
    const float* p2wr_wl = (const float*)d_in[22];
    const float* p2wr_bl = (const float*)d_in[23];
    const float* p2wr_wr = (const float*)d_in[24];
    const float* p2rv_wl = (const float*)d_in[25];
    const float* p2rv_bl = (const float*)d_in[26];
    const float* p2rv_wr = (const float*)d_in[27];
    const float* p2wb_wl = (const float*)d_in[28];
    const float* p2wb_bl = (const float*)d_in[29];
    const float* p2wb_wr = (const float*)d_in[30];
    const float* p2rb_wl = (const float*)d_in[31];
    const float* p2rb_bl = (const float*)d_in[32];
    const float* p2rb_wr = (const float*)d_in[33];

    // ---- workspace carve-up ----
    int* wsI = (int*)d_ws;
    int* cnt  = wsI + 0;            // 1.2M
    int* rp   = wsI + 1200000;      // 1.2M + 1
    int* rank = wsI + 2400004;      // 4M (per-edge rank, 4 relations)
    int* eidx = wsI + 6400004;      // 4M
    int* bsum = wsI + 10400004;     // 512
    float* wsF = (float*)d_ws + 10400768;   // 16B-aligned float region
    float* h_wr   = wsF + 0;         // dev  x16
    float* h_rv   = wsF + 1600000;   // dev  x16
    float* h_wb   = wsF + 3200000;   // task x16
    float* h_rb   = wsF + 11200000;  // task x16
    float* root_d = wsF + 19200000;  // dev  x16
    float* root_t = wsF + 20800000;  // task x16
    float* t1     = wsF + 28800000;  // task x16
    float* d1     = wsF + 36800000;  // dev  x16

    float* out = (float*)d_out;      // [d2: 100K x32 | t2: 500K x32]

    const int eblk = (NEDGE + 255) / 256;

    // ---- 1. CSR build (rank trick: fills are atomic-free) ----
    hipMemsetAsync(cnt, 0, (size_t)NCNT * sizeof(int), stream);
    hist_rank_rel<<<eblk, 256, 0, stream>>>(wr_dst, BASE_WR, cnt, rank + 0 * NEDGE);
    hist_rank_rel<<<eblk, 256, 0, stream>>>(rv_dst, BASE_RV, cnt, rank + 1 * NEDGE);
    hist_rank_rel<<<eblk, 256, 0, stream>>>(wb_dst, BASE_WB, cnt, rank + 2 * NEDGE);
    hist_rank_rel<<<eblk, 256, 0, stream>>>(rb_dst, BASE_RB, cnt, rank + 3 * NEDGE);
    scan_block_sums<<<SCAN_NBLK, 256, 0, stream>>>(cnt, bsum);
    scan_bsum<<<1, 512, 0, stream>>>(bsum);
    scan_final<<<SCAN_NBLK, 256, 0, stream>>>(cnt, bsum, rp);
    fill_rel<<<eblk, 256, 0, stream>>>(wr_src, wr_dst, rank + 0 * NEDGE, BASE_WR, rp, eidx);
    fill_rel<<<eblk, 256, 0, stream>>>(rv_src, rv_dst, rank + 1 * NEDGE, BASE_RV, rp, eidx);
    fill_rel<<<eblk, 256, 0, stream>>>(wb_src, wb_dst, rank + 2 * NEDGE, BASE_WB, rp, eidx);
    fill_rel<<<eblk, 256, 0, stream>>>(rb_src, rb_dst, rank + 3 * NEDGE, BASE_RB, rp, eidx);

    // ---- 2. pretransforms (h_rel + summed-root) ----
    pretransform_v4<<<(N_DEV + 511) / 512, 256, 0, stream>>>(
        x_dev, p1wr_wl, p1rv_wl, p1wb_wr, p1rb_wr, h_wr, h_rv, root_d, N_DEV);
    pretransform_v4<<<(N_TASK + 511) / 512, 256, 0, stream>>>(
        x_task, p1wb_wl, p1rb_wl, p1wr_wr, p1rv_wr, h_wb, h_rb, root_t, N_TASK);

    // ---- 3. L1 fused gathers ----
    gather_l1_v3<<<(N_TASK + 7) / 8, 256, 0, stream>>>(
        h_wr, h_rv, rp, eidx, BASE_WR, BASE_RV, root_t, p1wr_bl, p1rv_bl, t1, N_TASK);
    gather_l1_v3<<<(N_DEV + 7) / 8, 256, 0, stream>>>(
        h_wb, h_rb, rp, eidx, BASE_WB, BASE_RB, root_d, p1wb_bl, p1rb_bl, d1, N_DEV);

    // ---- 4. L2 fused gather + matmul -> d_out ----
    gather_l2_v3<<<(N_TASK + 31) / 32, 256, 0, stream>>>(
        d1, d1, rp, eidx, BASE_WR, BASE_RV, t1,
        p2wr_wl, p2rv_wl, p2wr_wr, p2rv_wr, p2wr_bl, p2rv_bl,
        out + (size_t)N_DEV * 32, N_TASK);
    gather_l2_v3<<<(N_DEV + 31) / 32, 256, 0, stream>>>(
        t1, t1, rp, eidx, BASE_WB, BASE_RB, d1,
        p2wb_wl, p2rb_wl, p2wb_wr, p2rb_wr, p2wb_bl, p2rb_bl,
        out, N_DEV);
}